// Round 2
// baseline (629.972 us; speedup 1.0000x reference)
//
#include <hip/hip_runtime.h>
#include <stdint.h>

// Problem constants (from setup_inputs): E=8, T=2048, D=2048, I=1024
constexpr int E_ = 8, T_ = 2048, D_ = 2048, I_ = 1024;
#define EPS_ 1e-6f
#define QMAX_ 127.0f

typedef int v4i __attribute__((ext_vector_type(4)));
typedef uint32_t __attribute__((address_space(1))) u32g_t;
typedef uint32_t __attribute__((address_space(3))) u32l_t;

// Direct global->LDS DMA, 16B per lane. LDS dest is wave-uniform base + lane*16.
__device__ __forceinline__ void load_lds16(const void* g, void* l) {
  __builtin_amdgcn_global_load_lds((u32g_t*)(uintptr_t)g, (u32l_t*)(uintptr_t)l,
                                   16, 0, 0);
}

// ---------------------------------------------------------------------------
// Fused column abs-max for x and guw (both [2048,2048] per expert):
// grid (cols/256, 32, E); y<16 -> x chunk y, y>=16 -> guw chunk y-16.
// partial[(e*16+rc)*cols + col] = max over 128 rows.
// ---------------------------------------------------------------------------
__global__ __launch_bounds__(256) void colmax_xw(
    const float* __restrict__ x, const float* __restrict__ guw,
    float* __restrict__ px, float* __restrict__ pw) {
  int e = blockIdx.z, rc = blockIdx.y;
  const float* src;
  float* dst;
  int rcc;
  if (rc < 16) { src = x;   dst = px; rcc = rc; }
  else         { src = guw; dst = pw; rcc = rc - 16; }
  int col = blockIdx.x * 256 + threadIdx.x;
  const float* p = src + ((size_t)e * 16 + rcc) * 128 * 2048 + col;
  float m = 0.f;
#pragma unroll 8
  for (int r = 0; r < 128; ++r) m = fmaxf(m, fabsf(p[(size_t)r * 2048]));
  dst[((size_t)e * 16 + rcc) * 2048 + col] = m;
}

// ---------------------------------------------------------------------------
// Stage-A column abs-max (single tensor): grid (cols/256, 16, E)
// ---------------------------------------------------------------------------
template <int RPC>
__global__ __launch_bounds__(256) void colmax_partial(
    const float* __restrict__ src, float* __restrict__ partial, int cols) {
  int e = blockIdx.z, rc = blockIdx.y;
  int col = blockIdx.x * 256 + threadIdx.x;
  const float* p = src + ((size_t)e * gridDim.y + rc) * RPC * cols + col;
  float m = 0.f;
#pragma unroll 8
  for (int r = 0; r < RPC; ++r) m = fmaxf(m, fabsf(p[(size_t)r * cols]));
  partial[((size_t)e * gridDim.y + rc) * cols + col] = m;
}

// ---------------------------------------------------------------------------
// s = max(sqrt(max(ax,EPS)/max(aw,EPS)), EPS), reducing 16 partials each
// grid: (cols/256, E)
// ---------------------------------------------------------------------------
__global__ __launch_bounds__(256) void compute_s(
    const float* __restrict__ px, const float* __restrict__ pw,
    float* __restrict__ s, int cols) {
  int e = blockIdx.y;
  int c = blockIdx.x * 256 + threadIdx.x;
  float ax = 0.f, aw = 0.f;
  for (int k = 0; k < 16; ++k) {
    ax = fmaxf(ax, px[((size_t)e * 16 + k) * cols + c]);
    aw = fmaxf(aw, pw[((size_t)e * 16 + k) * cols + c]);
  }
  float sv = sqrtf(fmaxf(ax, EPS_) / fmaxf(aw, EPS_));
  s[(size_t)e * cols + c] = fmaxf(sv, EPS_);
}

// ---------------------------------------------------------------------------
// Per-row quantize body (wave-per-row, shuffle-reduce, no LDS).
// v = src*s (MUL) or src/s; scale = max(rowmax|v|,EPS)/127;
// q = clip(rint(v/scale),-127,127).  Arithmetic identical to reference order.
// ---------------------------------------------------------------------------
template <bool MUL, int COLS>
__device__ __forceinline__ void quant_row_body(
    const float4* __restrict__ row4, const float4* __restrict__ s4,
    char4* __restrict__ qrow, float* __restrict__ rsc, int lane) {
  constexpr int NP = COLS / 256;
  float4 vv[NP];
  float m = 0.f;
#pragma unroll
  for (int i = 0; i < NP; ++i) {
    int c = i * 64 + lane;
    float4 rv = row4[c], sv = s4[c];
    float4 v;
    v.x = MUL ? rv.x * sv.x : rv.x / sv.x;
    v.y = MUL ? rv.y * sv.y : rv.y / sv.y;
    v.z = MUL ? rv.z * sv.z : rv.z / sv.z;
    v.w = MUL ? rv.w * sv.w : rv.w / sv.w;
    vv[i] = v;
    m = fmaxf(m, fmaxf(fmaxf(fabsf(v.x), fabsf(v.y)), fmaxf(fabsf(v.z), fabsf(v.w))));
  }
#pragma unroll
  for (int off = 32; off > 0; off >>= 1) m = fmaxf(m, __shfl_xor(m, off, 64));
  float scale = fmaxf(m, EPS_) / QMAX_;
#pragma unroll
  for (int i = 0; i < NP; ++i) {
    int c = i * 64 + lane;
    float4 v = vv[i];
    char4 o;
    o.x = (int8_t)fminf(fmaxf(rintf(v.x / scale), -QMAX_), QMAX_);
    o.y = (int8_t)fminf(fmaxf(rintf(v.y / scale), -QMAX_), QMAX_);
    o.z = (int8_t)fminf(fmaxf(rintf(v.z / scale), -QMAX_), QMAX_);
    o.w = (int8_t)fminf(fmaxf(rintf(v.w / scale), -QMAX_), QMAX_);
    qrow[c] = o;
  }
  if (lane == 0) *rsc = scale;
}

// Paired quantize: blocks [0, nrowsA/4) -> srcA with DIV, rest -> srcB with MUL.
// grid ((nrowsA+nrowsB)/4, E), block 256 (4 waves = 4 rows).
template <int COLS>
__global__ __launch_bounds__(256) void quant_pair(
    const float* __restrict__ srcA, const float* __restrict__ srcB,
    const float* __restrict__ s, int8_t* __restrict__ qA,
    int8_t* __restrict__ qB, float* __restrict__ rscA,
    float* __restrict__ rscB, int nrowsA, int nrowsB) {
  int e = blockIdx.y;
  int nbA = nrowsA >> 2;
  bool isB = (int)blockIdx.x >= nbA;
  int rb = isB ? (int)blockIdx.x - nbA : (int)blockIdx.x;
  int row = rb * 4 + (threadIdx.x >> 6);
  int lane = threadIdx.x & 63;
  const float4* s4 = (const float4*)(s + (size_t)e * COLS);
  if (isB) {
    const float4* row4 = (const float4*)(srcB + ((size_t)e * nrowsB + row) * COLS);
    char4* qrow = (char4*)(qB + ((size_t)e * nrowsB + row) * COLS);
    quant_row_body<true, COLS>(row4, s4, qrow, rscB + (size_t)e * nrowsB + row, lane);
  } else {
    const float4* row4 = (const float4*)(srcA + ((size_t)e * nrowsA + row) * COLS);
    char4* qrow = (char4*)(qA + ((size_t)e * nrowsA + row) * COLS);
    quant_row_body<false, COLS>(row4, s4, qrow, rscA + (size_t)e * nrowsA + row, lane);
  }
}

// ---------------------------------------------------------------------------
// int8 GEMM: C[m,n] = sum_k A[m,k]*B[n,k], dequant asc[m]*bsc[n].
// BM=128, BK=64, mfma_i32_16x16x64_i8 (one MFMA spans full BK).
// 4-slot LDS pipeline, prefetch distance 2, counted vmcnt (T3/T4):
//   prologue: DMA slots 0,1
//   iter ks:  DMA slot (ks+2)&3 ; s_waitcnt vmcnt(8/4/0) ; s_barrier ;
//             ds_read + MFMA (setprio 1)                      -- ONE barrier/step
// Slot-reuse proof: slot s overwritten at iter s+2(top) was last read at iter s;
// barrier B_{s+1} separates them (all waves' reads retire before their MFMAs).
// vmcnt is per-wave; wait-own-loads THEN barrier => all waves' chunks landed.
// LDS content swizzle via global source address (rule #21), read at
// slot = quad ^ ((l16>>1)&3): bank-conflict-free (verified round 1: 1.7e7->3e4).
// FUSE (GEMM1): BN=64, gate+up B tiles, SwiGLU epilogue + fused colmax of a.
// non-FUSE (GEMM2): BN=128. Both: slot = 16KB, 4 slots = 64KB, 2 blocks/CU.
// block 256 (4 waves 2x2), grid (NOUT/BN, T/128, E).
// ---------------------------------------------------------------------------
template <bool FUSE, int K, int NOUT, int BN>
__global__ __launch_bounds__(256) void gemm_i8(
    const int8_t* __restrict__ Aq, const int8_t* __restrict__ Bq,
    const float* __restrict__ asc, const float* __restrict__ bsc,
    float* __restrict__ outp, float* __restrict__ pmax) {
  constexpr int BM = 128, BK = 64;
  constexpr int NK = K / BK;
  constexpr int NBT = FUSE ? 2 : 1;              // B sub-tiles (gate/up)
  constexpr int SLOT = BM * 64 + NBT * BN * 64;  // 16384 bytes
  constexpr int NCH = SLOT / 1024;               // 16 DMA chunks per K-step
  constexpr int CPW = NCH / 4;                   // 4 chunks per wave
  constexpr int NT = BN / 32;                    // per-wave n-tiles
  static_assert(CPW == 4, "vmcnt literals assume 4 chunks/wave");
  __shared__ int8_t lds[4][SLOT];

  const int e = blockIdx.z;
  const int n0 = blockIdx.x * BN, m0 = blockIdx.y * BM;
  const int8_t* Ae = Aq + (size_t)e * T_ * K;
  const int8_t* Be = Bq + (size_t)e * 2048 * K;
  const int tid = threadIdx.x;
  const int lane = tid & 63, wv = tid >> 6;
  const int l16 = lane & 15, quad = lane >> 4;
  const int wm = wv & 1, wn = wv >> 1;
  const int lrow = lane >> 2;                              // row within chunk
  const int scol = ((lane & 3) ^ ((lane >> 3) & 3)) << 4;  // swizzled src slot
  const int swsel = ((quad ^ ((l16 >> 1) & 3)) << 4);      // swizzled read slot

  // Per-wave DMA chunk tables (chunk = 16 rows x 64B, HW: lane i -> dst+i*16)
  const int8_t* gsrc[CPW];
  int loff[CPW];
#pragma unroll
  for (int i = 0; i < CPW; ++i) {
    int c = wv * CPW + i;
    if (c < 8) {  // A rows [c*16, c*16+16)
      gsrc[i] = Ae + (size_t)(m0 + c * 16 + lrow) * K + scol;
      loff[i] = c * 1024;
    } else {  // B chunks
      int cc = c - 8;
      int br;
      if (FUSE) br = n0 + (cc >= 4 ? I_ : 0) + (cc & 3) * 16 + lrow;
      else      br = n0 + cc * 16 + lrow;
      gsrc[i] = Be + (size_t)br * K + scol;
      loff[i] = 8192 + cc * 1024;
    }
  }

  v4i accg[4][NT], accu[4][NT];
#pragma unroll
  for (int mt = 0; mt < 4; ++mt)
#pragma unroll
    for (int nt = 0; nt < NT; ++nt) {
      accg[mt][nt] = (v4i){0, 0, 0, 0};
      accu[mt][nt] = (v4i){0, 0, 0, 0};
    }

  auto issue = [&](int ksrc, int slot) {
#pragma unroll
    for (int i = 0; i < CPW; ++i)
      load_lds16(gsrc[i] + (size_t)ksrc * BK, &lds[slot][loff[i]]);
  };

  // prologue: stage K-steps 0,1 into slots 0,1  (NK >= 2 always here)
  issue(0, 0);
  issue(1, 1);

  for (int ks = 0; ks < NK; ++ks) {
    const int sl = ks & 3;
    if (ks + 2 < NK) issue(ks + 2, (ks + 2) & 3);
    const int rem = NK - 1 - ks;
    if (rem >= 2)      asm volatile("s_waitcnt vmcnt(8)" ::: "memory");
    else if (rem == 1) asm volatile("s_waitcnt vmcnt(4)" ::: "memory");
    else               asm volatile("s_waitcnt vmcnt(0)" ::: "memory");
    __builtin_amdgcn_s_barrier();
    __builtin_amdgcn_sched_barrier(0);

    const int8_t* La = &lds[sl][0];
    const int8_t* Lb = &lds[sl][8192];
    v4i af[4];
#pragma unroll
    for (int mt = 0; mt < 4; ++mt)
      af[mt] = *(const v4i*)(La + (wm * 64 + mt * 16 + l16) * 64 + swsel);
    v4i bf0[NT], bf1[NT];
#pragma unroll
    for (int nt = 0; nt < NT; ++nt) {
      int br = wn * (BN / 2) + nt * 16 + l16;
      bf0[nt] = *(const v4i*)(Lb + br * 64 + swsel);
      if (FUSE) bf1[nt] = *(const v4i*)(Lb + 4096 + br * 64 + swsel);
    }
    __builtin_amdgcn_s_setprio(1);
#pragma unroll
    for (int mt = 0; mt < 4; ++mt)
#pragma unroll
      for (int nt = 0; nt < NT; ++nt) {
        accg[mt][nt] = __builtin_amdgcn_mfma_i32_16x16x64_i8(
            af[mt], bf0[nt], accg[mt][nt], 0, 0, 0);
        if (FUSE)
          accu[mt][nt] = __builtin_amdgcn_mfma_i32_16x16x64_i8(
              af[mt], bf1[nt], accu[mt][nt], 0, 0, 0);
      }
    __builtin_amdgcn_s_setprio(0);
  }

  const float* ascE = asc + (size_t)e * T_;
  const float* bscE = bsc + (size_t)e * 2048;
  float cml[NT];
#pragma unroll
  for (int nt = 0; nt < NT; ++nt) cml[nt] = 0.f;
#pragma unroll
  for (int mt = 0; mt < 4; ++mt)
#pragma unroll
    for (int nt = 0; nt < NT; ++nt)
#pragma unroll
      for (int r2 = 0; r2 < 4; ++r2) {
        int grow = m0 + wm * 64 + mt * 16 + quad * 4 + r2;
        int gcol = n0 + wn * (BN / 2) + nt * 16 + l16;
        float as = ascE[grow];
        if (FUSE) {
          float g = (float)accg[mt][nt][r2] * as * bscE[gcol];
          float u = (float)accu[mt][nt][r2] * as * bscE[I_ + gcol];
          float sg = g / (1.0f + expf(-g));  // silu
          float av = sg * u;
          outp[(size_t)e * T_ * NOUT + (size_t)grow * NOUT + gcol] = av;
          cml[nt] = fmaxf(cml[nt], fabsf(av));
        } else {
          outp[(size_t)e * T_ * NOUT + (size_t)grow * NOUT + gcol] =
              (float)accg[mt][nt][r2] * as * bscE[gcol];
        }
      }

  if (FUSE) {
    // Fused column-absmax of a over this block's 128 rows, colmax layout:
    // pmax[(e*16 + by)*NOUT + col]. float-bits atomicMax valid (all >= 0).
    // Scratch lives in lds[0][0..255]; last compute slot is lds[3] (NK%4==0).
    float* cmax = (float*)&lds[0][0];
    if (tid < BN) cmax[tid] = 0.f;
    __syncthreads();
#pragma unroll
    for (int nt = 0; nt < NT; ++nt)
      atomicMax((int*)&cmax[wn * (BN / 2) + nt * 16 + l16],
                __float_as_int(cml[nt]));
    __syncthreads();
    if (tid < BN)
      pmax[((size_t)e * 16 + blockIdx.y) * NOUT + n0 + tid] = cmax[tid];
  }
}

// ---------------------------------------------------------------------------
extern "C" void kernel_launch(void* const* d_in, const int* in_sizes, int n_in,
                              void* d_out, int out_size, void* d_ws, size_t ws_size,
                              hipStream_t stream) {
  const float* x   = (const float*)d_in[0];   // [E,T,D]
  const float* guw = (const float*)d_in[1];   // [E,2I,D]
  const float* dw  = (const float*)d_in[2];   // [E,D,I]
  float* out = (float*)d_out;                 // [E,T,D] fp32

  char* ws = (char*)d_ws;
  size_t off = 0;
  auto alloc = [&](size_t bytes) { char* p = ws + off; off += bytes; return p; };
  int8_t* xq   = (int8_t*)alloc((size_t)E_ * T_ * D_);        // 32 MB
  int8_t* wq1  = (int8_t*)alloc((size_t)E_ * 2 * I_ * D_);    // 32 MB
  int8_t* aq   = (int8_t*)alloc((size_t)E_ * T_ * I_);        // 16 MB
  int8_t* dwq  = (int8_t*)alloc((size_t)E_ * D_ * I_);        // 16 MB
  float*  a    = (float*)alloc((size_t)E_ * T_ * I_ * 4);     // 64 MB
  float*  px   = (float*)alloc((size_t)E_ * 16 * D_ * 4);
  float*  pw   = (float*)alloc((size_t)E_ * 16 * D_ * 4);
  float*  pdw  = (float*)alloc((size_t)E_ * 16 * I_ * 4);
  float*  pa   = (float*)alloc((size_t)E_ * 16 * I_ * 4);
  float*  s1   = (float*)alloc((size_t)E_ * D_ * 4);
  float*  s2   = (float*)alloc((size_t)E_ * I_ * 4);
  float*  xsc  = (float*)alloc((size_t)E_ * T_ * 4);
  float*  wsc1 = (float*)alloc((size_t)E_ * 2 * I_ * 4);
  float*  asc  = (float*)alloc((size_t)E_ * T_ * 4);
  float*  dwsc = (float*)alloc((size_t)E_ * D_ * 4);

  dim3 b(256);
  // Linear 1 smoothing scales: x and guw colmax fused (same shape)
  colmax_xw<<<dim3(D_ / 256, 32, E_), b, 0, stream>>>(x, guw, px, pw);
  colmax_partial<128><<<dim3(I_ / 256, 16, E_), b, 0, stream>>>(dw, pdw, I_);
  compute_s<<<dim3(D_ / 256, E_), b, 0, stream>>>(px, pw, s1, D_);
  // Quantize x (div) + guw (mul) in one dispatch
  quant_pair<D_><<<dim3((T_ + 2 * I_) / 4, E_), b, 0, stream>>>(
      x, guw, s1, xq, wq1, xsc, wsc1, T_, 2 * I_);
  // GEMM1 + SwiGLU -> a [E,T,I]; epilogue also emits colmax partials of a
  gemm_i8<true, D_, I_, 64><<<dim3(I_ / 64, T_ / 128, E_), b, 0, stream>>>(
      xq, wq1, xsc, wsc1, a, pa);
  // Linear 2 smoothing scales (pa produced by GEMM1 epilogue)
  compute_s<<<dim3(I_ / 256, E_), b, 0, stream>>>(pa, pdw, s2, I_);
  // Quantize a (div) + dw (mul) in one dispatch
  quant_pair<I_><<<dim3((T_ + D_) / 4, E_), b, 0, stream>>>(
      a, dw, s2, aq, dwq, asc, dwsc, T_, D_);
  // GEMM2 -> out [E,T,D], 128x128 tile
  gemm_i8<false, I_, D_, 128><<<dim3(D_ / 128, T_ / 128, E_), b, 0, stream>>>(
      aq, dwq, asc, dwsc, out, nullptr);
}